// Round 5
// baseline (168.950 us; speedup 1.0000x reference)
//
#include <hip/hip_runtime.h>

// LearnableTD reverse affine suffix scan, v4: ONE WAVE PER ROW.
// 64 lanes x 32 elems = T=2048. No __syncthreads, no LDS -> no convoy
// effect; each wave issues ~36 float4 loads upfront for max MLP.
//   b_t   = g*(1-d_t)*l_t
//   lam_t = [r_t + g*(1-d_t)*(1-l_t)*v_{t+1}] + b_t * lam_{t+1}
//   sum_t = [r_t]                             + b_t * sum_{t+1}

#define TPB 256
#define EPT 32            // elems per lane; requires T == 64*EPT

typedef float v4f __attribute__((ext_vector_type(4)));

struct Aff { float aL, aS, b; };

__device__ inline Aff compose(const Aff& L, const Aff& R) {
    Aff o;
    o.aL = fmaf(L.b, R.aL, L.aL);
    o.aS = fmaf(L.b, R.aS, L.aS);
    o.b  = L.b * R.b;
    return o;
}

// lam[t] = 0.9 + 0.1*sigmoid(raw_lambd[start+t]);  lam[T] = gamma
__global__ void precompute_kernel(const float* __restrict__ raw_gamma,
                                  const float* __restrict__ raw_lambd,
                                  const int* __restrict__ start_p,
                                  float* __restrict__ lam, int T) {
    int t = blockIdx.x * blockDim.x + threadIdx.x;
    if (t < T) lam[t] = 0.9f + 0.1f / (1.0f + __expf(-raw_lambd[start_p[0] + t]));
    if (t == 0) lam[T] = 0.98f + 0.02f / (1.0f + __expf(-raw_gamma[0]));
}

__global__ __launch_bounds__(TPB)
void td_scan_kernel(const float* __restrict__ values,    // B x (T+1)
                    const float* __restrict__ rewards,   // B x T
                    const float* __restrict__ dones,     // B x T
                    const float* __restrict__ lam_arr,   // T lambdas + [T]=g
                    float* __restrict__ out,             // B*(T+1) lam ++ B*T sum
                    int B, int T)
{
    const int lane = threadIdx.x & 63;
    const int b    = blockIdx.x * (TPB / 64) + (threadIdx.x >> 6);  // row
    if (b >= B) return;

    const float g = lam_arr[T];                      // uniform

    const size_t rowV = (size_t)b * (T + 1);
    const float* rrow = rewards + (size_t)b * T;
    const float* drow = dones   + (size_t)b * T;
    const int base = lane * EPT;                     // local t of chunk start

    // ---------- issue all loads ----------
    v4f R4[8], D4[8], L4[8];
    #pragma unroll
    for (int j = 0; j < 8; ++j) {
        R4[j] = *(const v4f*)(rrow + base + 4 * j);
        D4[j] = *(const v4f*)(drow + base + 4 * j);
        L4[j] = *(const v4f*)(lam_arr + base + 4 * j);
    }
    // values window: need vrow[base+1 .. base+32]; stage aligned + shift.
    const int off = (int)((rowV + 1) & 3);           // wave-uniform
    const float* wbase = values + (rowV + 1 - off) + base;  // 16B-aligned
    float w[36];
    #pragma unroll
    for (int j = 0; j < 8; ++j) *(v4f*)(w + 4 * j) = *(const v4f*)(wbase + 4 * j);
    w[32] = w[33] = w[34] = w[35] = 0.0f;
    if (off) {                                        // uniform branch
        const size_t gidx = (rowV + 1 - off) + base + 32;
        const size_t totalV = (size_t)B * (T + 1);
        #pragma unroll
        for (int c = 0; c < 3; ++c)
            if (gidx + c < totalV) w[32 + c] = values[gidx + c];
    }
    const float vT = values[rowV + T];               // uniform addr (broadcast)

    // ---------- select vn, build affine maps ----------
    float vn[32];
    switch (off) {
    case 0: { 
        #pragma unroll
        for (int k = 0; k < 32; ++k) vn[k] = w[k];     } break;
    case 1: { 
        #pragma unroll
        for (int k = 0; k < 32; ++k) vn[k] = w[k + 1]; } break;
    case 2: { 
        #pragma unroll
        for (int k = 0; k < 32; ++k) vn[k] = w[k + 2]; } break;
    default: { 
        #pragma unroll
        for (int k = 0; k < 32; ++k) vn[k] = w[k + 3]; } break;
    }

    float bb[32], aL[32], aS[32];
    #pragma unroll
    for (int k = 0; k < 32; ++k) {
        const float rr = R4[k >> 2][k & 3];
        const float dd = D4[k >> 2][k & 3];
        const float ll = L4[k >> 2][k & 3];
        const float cont = g * (1.0f - dd);
        bb[k] = cont * ll;
        aL[k] = fmaf(cont * (1.0f - ll), vn[k], rr);
        aS[k] = rr;
    }

    // ---------- tree composite of the 32 maps ----------
    Aff C4[8];
    #pragma unroll
    for (int c = 0; c < 8; ++c) {
        Aff m0 = { aL[4*c+0], aS[4*c+0], bb[4*c+0] };
        Aff m1 = { aL[4*c+1], aS[4*c+1], bb[4*c+1] };
        Aff m2 = { aL[4*c+2], aS[4*c+2], bb[4*c+2] };
        Aff m3 = { aL[4*c+3], aS[4*c+3], bb[4*c+3] };
        C4[c] = compose(compose(m0, m1), compose(m2, m3));
    }
    Aff c2a = compose(C4[0], C4[1]), c2b = compose(C4[2], C4[3]);
    Aff c2c = compose(C4[4], C4[5]), c2d = compose(C4[6], C4[7]);
    Aff c3a = compose(c2a, c2b);
    Aff S_hi = compose(c2c, c2d);        // composite of local elems 16..31
    Aff C = compose(c3a, S_hi);          // full-chunk composite

    // ---------- wave-level inclusive suffix scan ----------
    Aff S = C;
    #pragma unroll
    for (int dlt = 1; dlt < 64; dlt <<= 1) {
        Aff o;
        o.aL = __shfl_down(S.aL, dlt, 64);
        o.aS = __shfl_down(S.aS, dlt, 64);
        o.b  = __shfl_down(S.b,  dlt, 64);
        if (lane + dlt < 64) S = compose(S, o);
    }
    Aff E;                                // exclusive suffix (right of chunk)
    E.aL = __shfl_down(S.aL, 1, 64);
    E.aS = __shfl_down(S.aS, 1, 64);
    E.b  = __shfl_down(S.b,  1, 64);
    if (lane == 63) { E.aL = 0.0f; E.aS = 0.0f; E.b = 1.0f; }

    float xL = fmaf(E.b, vT, E.aL);       // carry at chunk right boundary
    float xS = E.aS;                      // sum carry-in is 0

    // ---------- apply carry (two 16-chains in parallel) ----------
    float xmL = fmaf(S_hi.b, xL, S_hi.aL);   // carry at local idx 16 boundary
    float xmS = fmaf(S_hi.b, xS, S_hi.aS);
    // overwrite aL->lam outputs, aS->sum outputs (in place)
    #pragma unroll
    for (int k = 15; k >= 0; --k) {
        const int kb = k + 16;
        xL  = fmaf(bb[kb], xL,  aL[kb]);  xS  = fmaf(bb[kb], xS,  aS[kb]);
        aL[kb] = xL;  aS[kb] = xS;
        xmL = fmaf(bb[k],  xmL, aL[k]);   xmS = fmaf(bb[k],  xmS, aS[k]);
        aL[k] = xmL;  aS[k] = xmS;
    }

    // ---------- sum_rewards: rows 16B-aligned, direct f4 stores ----------
    float* sum_out = out + (size_t)B * (T + 1) + (size_t)b * T + base;
    #pragma unroll
    for (int j = 0; j < 8; ++j) {
        v4f s = { aS[4*j], aS[4*j+1], aS[4*j+2], aS[4*j+3] };
        *(v4f*)(sum_out + 4 * j) = s;
    }

    // ---------- lambda_returns: in-register shift to aligned f4 ----------
    const size_t O = (size_t)b * (T + 1);
    float* lamrow = out + O;
    const int sh = (int)((4 - (O & 3)) & 3);         // wave-uniform
    float nb0 = __shfl_down(aL[0], 1, 64);
    float nb1 = __shfl_down(aL[1], 1, 64);
    float nb2 = __shfl_down(aL[2], 1, 64);
    if (lane == 63) nb0 = vT;                        // elem at t = T

    float z[32];                                     // z[m] = elem local sh+m
    switch (sh) {
    case 0: { 
        #pragma unroll
        for (int m = 0; m < 32; ++m) z[m] = aL[m];
        } break;
    case 1: { 
        #pragma unroll
        for (int m = 0; m < 31; ++m) z[m] = aL[m + 1];
        z[31] = nb0; } break;
    case 2: { 
        #pragma unroll
        for (int m = 0; m < 30; ++m) z[m] = aL[m + 2];
        z[30] = nb0; z[31] = nb1; } break;
    default: { 
        #pragma unroll
        for (int m = 0; m < 29; ++m) z[m] = aL[m + 3];
        z[29] = nb0; z[30] = nb1; z[31] = nb2; } break;
    }
    #pragma unroll
    for (int j = 0; j < 8; ++j) {
        const int t0 = base + sh + 4 * j;
        if (t0 + 3 <= T) {                 // always true for lane<63
            v4f v = { z[4*j], z[4*j+1], z[4*j+2], z[4*j+3] };
            *(v4f*)(lamrow + t0) = v;
        }
    }
    if (lane == 0) {                       // row head (< 4 scalars)
        for (int m = 0; m < sh; ++m) lamrow[m] = aL[m];
    }
    if (lane == 63) {                      // row tail leftovers (< 4 scalars)
        const int J  = (sh <= 1) ? 8 : 7;              // groups stored above
        const int LC = (33 - sh) & 3;                  // leftover count
        const int firstLocal = sh + 4 * J;             // first unstored local
        for (int m = 0; m < LC; ++m) {
            const int loc = firstLocal + m;
            lamrow[base + loc] = (loc < 32) ? aL[loc] : vT;
        }
    }
}

extern "C" void kernel_launch(void* const* d_in, const int* in_sizes, int n_in,
                              void* d_out, int out_size, void* d_ws, size_t ws_size,
                              hipStream_t stream) {
    const float* values    = (const float*)d_in[0];
    const float* rewards   = (const float*)d_in[1];
    const float* dones     = (const float*)d_in[2];
    const float* raw_gamma = (const float*)d_in[3];
    const float* raw_lambd = (const float*)d_in[4];
    const int*   start_idx = (const int*)d_in[5];
    float* out = (float*)d_out;
    float* lam_arr = (float*)d_ws;         // T lambdas + 1 gamma

    const int n_values  = in_sizes[0];     // B*(T+1)
    const int n_rewards = in_sizes[1];     // B*T
    const int B = n_values - n_rewards;
    const int T = n_rewards / B;           // layout requires T == 64*EPT

    precompute_kernel<<<(T + 256) / 256, 256, 0, stream>>>(raw_gamma, raw_lambd,
                                                           start_idx, lam_arr, T);
    const int rowsPerBlock = TPB / 64;
    td_scan_kernel<<<(B + rowsPerBlock - 1) / rowsPerBlock, TPB, 0, stream>>>(
        values, rewards, dones, lam_arr, out, B, T);
}

// Round 6
// 157.091 us; speedup vs baseline: 1.0755x; 1.0755x over previous
//
#include <hip/hip_runtime.h>

// LearnableTD reverse affine suffix scan, v5.
// One block (256 thr) per row, 8 elems/thread, single pass.
// ALL global accesses are aligned 16B vector ops:
//  - vn (values[t+1], misaligned by construction) via 3 aligned f4 loads +
//    block-uniform in-register shift select (no LDS, no scalar loads)
//  - lambda-row stores via register shift + 3-float LDS boundary exchange
// Cross-wave combine: each thread composes the <=3 wave composites to its
// right (no tid0-serial section). Normal (cached) stores.

#define TPB 256
#define EPT 8
#define NW  (TPB / 64)

typedef float v4f __attribute__((ext_vector_type(4)));

struct Aff { float aL, aS, b; };

__device__ inline Aff compose(const Aff& L, const Aff& R) {
    Aff o;
    o.aL = fmaf(L.b, R.aL, L.aL);
    o.aS = fmaf(L.b, R.aS, L.aS);
    o.b  = L.b * R.b;
    return o;
}

// lam[t] = 0.9 + 0.1*sigmoid(raw_lambd[start+t]);  lam[T] = gamma
__global__ void precompute_kernel(const float* __restrict__ raw_gamma,
                                  const float* __restrict__ raw_lambd,
                                  const int* __restrict__ start_p,
                                  float* __restrict__ lam, int T) {
    int t = blockIdx.x * blockDim.x + threadIdx.x;
    if (t < T) lam[t] = 0.9f + 0.1f / (1.0f + __expf(-raw_lambd[start_p[0] + t]));
    if (t == 0) lam[T] = 0.98f + 0.02f / (1.0f + __expf(-raw_gamma[0]));
}

__global__ __launch_bounds__(TPB, 8)
void td_scan_kernel(const float* __restrict__ values,    // B x (T+1)
                    const float* __restrict__ rewards,   // B x T
                    const float* __restrict__ dones,     // B x T
                    const float* __restrict__ lam_arr,   // T lambdas + [T]=g
                    float* __restrict__ out,             // B*(T+1) lam ++ B*T sum
                    int B, int T)
{
    __shared__ float s_wAL[NW], s_wAS[NW], s_wB[NW];
    __shared__ float s_head[3 * TPB];

    const int b    = blockIdx.x;
    const int tid  = threadIdx.x;
    const int lane = tid & 63;
    const int wave = tid >> 6;

    const float g = lam_arr[T];
    const size_t rowV = (size_t)b * (T + 1);
    const float* rrow = rewards + (size_t)b * T;
    const float* drow = dones   + (size_t)b * T;
    const int base = tid * EPT;

    // ---------- all loads, all aligned f4 ----------
    const v4f r0 = *(const v4f*)(rrow + base);
    const v4f r1 = *(const v4f*)(rrow + base + 4);
    const v4f d0 = *(const v4f*)(drow + base);
    const v4f d1 = *(const v4f*)(drow + base + 4);
    const v4f l0 = *(const v4f*)(lam_arr + base);
    const v4f l1 = *(const v4f*)(lam_arr + base + 4);

    const int off = (int)((rowV + 1) & 3);          // block-uniform
    const size_t gA = (rowV + 1 - off) + base;      // 16B-aligned
    float w[12];
    *(v4f*)(w)     = *(const v4f*)(values + gA);
    *(v4f*)(w + 4) = *(const v4f*)(values + gA + 4);
    w[8] = w[9] = w[10] = w[11] = 0.0f;
    if (off) {                                      // w2 only needed if off>0
        const size_t totalV = (size_t)B * (T + 1);
        if (gA + 11 < totalV) {
            *(v4f*)(w + 8) = *(const v4f*)(values + gA + 8);
        } else {                                    // last thread of last row
            #pragma unroll
            for (int c = 0; c < 4; ++c)
                if (gA + 8 + c < totalV) w[8 + c] = values[gA + 8 + c];
        }
    }
    const float vT = values[rowV + T];              // uniform -> scalar load

    // ---------- vn select (block-uniform shift) ----------
    float vn[EPT];
    switch (off) {
    case 0: { 
        #pragma unroll
        for (int k = 0; k < EPT; ++k) vn[k] = w[k];     } break;
    case 1: { 
        #pragma unroll
        for (int k = 0; k < EPT; ++k) vn[k] = w[k + 1]; } break;
    case 2: { 
        #pragma unroll
        for (int k = 0; k < EPT; ++k) vn[k] = w[k + 2]; } break;
    default: { 
        #pragma unroll
        for (int k = 0; k < EPT; ++k) vn[k] = w[k + 3]; } break;
    }

    // ---------- affine maps ----------
    float rr[EPT] = { r0.x, r0.y, r0.z, r0.w, r1.x, r1.y, r1.z, r1.w };
    float dd[EPT] = { d0.x, d0.y, d0.z, d0.w, d1.x, d1.y, d1.z, d1.w };
    float ll[EPT] = { l0.x, l0.y, l0.z, l0.w, l1.x, l1.y, l1.z, l1.w };
    float bb[EPT], aL[EPT], aS[EPT];
    #pragma unroll
    for (int k = 0; k < EPT; ++k) {
        const float cont = g * (1.0f - dd[k]);
        bb[k] = cont * ll[k];
        aL[k] = fmaf(cont * (1.0f - ll[k]), vn[k], rr[k]);
        aS[k] = rr[k];
    }

    // ---------- depth-3 tree composite of the 8 maps ----------
    Aff m[EPT];
    #pragma unroll
    for (int k = 0; k < EPT; ++k) { m[k].aL = aL[k]; m[k].aS = aS[k]; m[k].b = bb[k]; }
    Aff c01 = compose(m[0], m[1]), c23 = compose(m[2], m[3]);
    Aff c45 = compose(m[4], m[5]), c67 = compose(m[6], m[7]);
    Aff c03 = compose(c01, c23),   c47 = compose(c45, c67);
    Aff C   = compose(c03, c47);

    // ---------- wave-level inclusive suffix scan ----------
    Aff S = C;
    #pragma unroll
    for (int dlt = 1; dlt < 64; dlt <<= 1) {
        Aff o;
        o.aL = __shfl_down(S.aL, dlt, 64);
        o.aS = __shfl_down(S.aS, dlt, 64);
        o.b  = __shfl_down(S.b,  dlt, 64);
        if (lane + dlt < 64) S = compose(S, o);
    }
    Aff E;                                          // exclusive (right of thread)
    E.aL = __shfl_down(S.aL, 1, 64);
    E.aS = __shfl_down(S.aS, 1, 64);
    E.b  = __shfl_down(S.b,  1, 64);
    if (lane == 63) { E.aL = 0.0f; E.aS = 0.0f; E.b = 1.0f; }

    if (lane == 0) { s_wAL[wave] = S.aL; s_wAS[wave] = S.aS; s_wB[wave] = S.b; }
    __syncthreads();

    // ---------- per-thread compose of wave composites to the right ----------
    float cL = vT, cS = 0.0f;
    #pragma unroll
    for (int wv = NW - 1; wv >= 1; --wv) {
        if (wv > wave) {
            const float wb = s_wB[wv];
            cL = fmaf(wb, cL, s_wAL[wv]);
            cS = fmaf(wb, cS, s_wAS[wv]);
        }
    }

    // ---------- apply carry right-to-left ----------
    float xL = fmaf(E.b, cL, E.aL);
    float xS = fmaf(E.b, cS, E.aS);
    #pragma unroll
    for (int k = EPT - 1; k >= 0; --k) {
        xL = fmaf(bb[k], xL, aL[k]);  aL[k] = xL;   // aL -> lambda outputs
        xS = fmaf(bb[k], xS, aS[k]);  aS[k] = xS;   // aS -> sum outputs
    }

    // ---------- sum_rewards: aligned f4 stores ----------
    float* sum_out = out + (size_t)B * (T + 1) + (size_t)b * T + base;
    v4f s0 = { aS[0], aS[1], aS[2], aS[3] };
    v4f s1 = { aS[4], aS[5], aS[6], aS[7] };
    *(v4f*)(sum_out)     = s0;
    *(v4f*)(sum_out + 4) = s1;

    // ---------- lambda_returns: aligned f4 via register shift ----------
    float* lamrow = out + rowV;
    const int sh = (int)((4 - (rowV & 3)) & 3);     // block-uniform
    if (sh == 0) {
        v4f p0 = { aL[0], aL[1], aL[2], aL[3] };
        v4f p1 = { aL[4], aL[5], aL[6], aL[7] };
        *(v4f*)(lamrow + base)     = p0;
        *(v4f*)(lamrow + base + 4) = p1;
        if (tid == 0) lamrow[T] = vT;
    } else {
        s_head[3 * tid]     = aL[0];
        s_head[3 * tid + 1] = aL[1];
        s_head[3 * tid + 2] = aL[2];
        __syncthreads();
        float nb0 = vT, nb1 = 0.0f, nb2 = 0.0f;
        if (tid < TPB - 1) {
            nb0 = s_head[3 * tid + 3];
            nb1 = s_head[3 * tid + 4];
            nb2 = s_head[3 * tid + 5];
        }
        float z[EPT];
        switch (sh) {
        case 1: { 
            #pragma unroll
            for (int k = 0; k < 7; ++k) z[k] = aL[k + 1];
            z[7] = nb0; } break;
        case 2: { 
            #pragma unroll
            for (int k = 0; k < 6; ++k) z[k] = aL[k + 2];
            z[6] = nb0; z[7] = nb1; } break;
        default: { 
            #pragma unroll
            for (int k = 0; k < 5; ++k) z[k] = aL[k + 3];
            z[5] = nb0; z[6] = nb1; z[7] = nb2; } break;
        }
        v4f p0 = { z[0], z[1], z[2], z[3] };
        *(v4f*)(lamrow + base + sh) = p0;           // covers <= T always
        if (tid < TPB - 1 || sh == 1) {
            v4f p1 = { z[4], z[5], z[6], z[7] };
            *(v4f*)(lamrow + base + sh + 4) = p1;
        } else {                                    // last thread, sh in {2,3}
            #pragma unroll
            for (int k = 4; k < EPT; ++k)
                if (base + sh + k <= T) lamrow[base + sh + k] = z[k];
        }
        if (tid == 0)
            for (int k = 0; k < sh; ++k) lamrow[k] = aL[k];
    }
}

extern "C" void kernel_launch(void* const* d_in, const int* in_sizes, int n_in,
                              void* d_out, int out_size, void* d_ws, size_t ws_size,
                              hipStream_t stream) {
    const float* values    = (const float*)d_in[0];
    const float* rewards   = (const float*)d_in[1];
    const float* dones     = (const float*)d_in[2];
    const float* raw_gamma = (const float*)d_in[3];
    const float* raw_lambd = (const float*)d_in[4];
    const int*   start_idx = (const int*)d_in[5];
    float* out = (float*)d_out;
    float* lam_arr = (float*)d_ws;         // T lambdas + 1 gamma

    const int n_values  = in_sizes[0];     // B*(T+1)
    const int n_rewards = in_sizes[1];     // B*T
    const int B = n_values - n_rewards;
    const int T = n_rewards / B;           // layout assumes T == TPB*EPT

    precompute_kernel<<<(T + 256) / 256, 256, 0, stream>>>(raw_gamma, raw_lambd,
                                                           start_idx, lam_arr, T);
    td_scan_kernel<<<B, TPB, 0, stream>>>(values, rewards, dones, lam_arr, out, B, T);
}